// Round 9
// baseline (94.072 us; speedup 1.0000x reference)
//
#include <hip/hip_runtime.h>

#define MARGIN 0.2f
#define EPS 1e-8f
#define GRID_BLOCKS 2048

typedef float f32x2 __attribute__((ext_vector_type(2)));

// ---- kernel 1: fp32 -> fp8(e4m3) convert + zero accumulators --------------

__global__ __launch_bounds__(256) void convert_kernel(
    const float* __restrict__ batch,
    unsigned char* __restrict__ batch8,
    float* __restrict__ acc,            // acc[0]=loss, acc[1]=cnt, acc[2]=ticket
    int n8)
{
    int i = blockIdx.x * blockDim.x + threadIdx.x;
    if (i == 0) {
        acc[0] = 0.f;
        acc[1] = 0.f;
        ((unsigned*)acc)[2] = 0u;
    }
    if (i < n8) {
        const float4* src = (const float4*)(batch + (size_t)i * 8);
        float4 f0 = src[0];
        float4 f1 = src[1];
        int lo = __builtin_amdgcn_cvt_pk_fp8_f32(f0.x, f0.y, 0, false);
        lo     = __builtin_amdgcn_cvt_pk_fp8_f32(f0.z, f0.w, lo, true);
        int hi = __builtin_amdgcn_cvt_pk_fp8_f32(f1.x, f1.y, 0, false);
        hi     = __builtin_amdgcn_cvt_pk_fp8_f32(f1.z, f1.w, hi, true);
        uint2 w;
        w.x = (unsigned)lo;
        w.y = (unsigned)hi;
        *(uint2*)(batch8 + (size_t)i * 8) = w;
    }
}

// ---- kernel 2: fp8 gather main + last-block finalize ----------------------
// 8 lanes/triplet, 8 triplets/wave, unroll x2. Row = 128 fp8 = 128B; lane fi
// loads uint4 at byte fi*16 -> one wave instruction covers 8 full rows.
// Triplet indices / labels / beta read directly (8-lane groups broadcast the
// same address). Index loads for both unrolled triplets issue first, row
// loads next, beta last -> the label->beta chain hides under row latency.
// Block partials go through 2 global atomics; the last block (ticket) does
// the final division and writes out[0]. Two dispatches total.
__global__ __launch_bounds__(256) void triplet_main_kernel(
    const unsigned char* __restrict__ batch8,
    const int* __restrict__ labels,
    const int* __restrict__ triplets,
    const float* __restrict__ beta,
    float* __restrict__ acc,            // acc[0]=loss, acc[1]=cnt, acc[2]=ticket
    float* __restrict__ out,
    int T)
{
    const int lane = threadIdx.x & 63;
    const int wid  = threadIdx.x >> 6;   // wave 0..3
    const int sub  = lane >> 3;          // triplet slot 0..7
    const int fi   = lane & 7;           // 16B chunk 0..7 within row
    const int boff = fi << 4;

    float loss = 0.f, cnt = 0.f;
    const int Tm1 = T - 1;

    auto ldrow = [&](int row) {
        return *(const uint4*)(batch8 + ((size_t)(unsigned)row << 7) + boff);
    };
    auto accum = [&](const uint4& A, const uint4& P, const uint4& N,
                     float& sap, float& san) {
        #pragma unroll
        for (int w = 0; w < 4; ++w) {
            unsigned aw = (&A.x)[w];
            unsigned pw = (&P.x)[w];
            unsigned nw = (&N.x)[w];
            f32x2 a0 = __builtin_amdgcn_cvt_pk_f32_fp8(aw, false);
            f32x2 a1 = __builtin_amdgcn_cvt_pk_f32_fp8(aw, true);
            f32x2 p0 = __builtin_amdgcn_cvt_pk_f32_fp8(pw, false);
            f32x2 p1 = __builtin_amdgcn_cvt_pk_f32_fp8(pw, true);
            f32x2 n0 = __builtin_amdgcn_cvt_pk_f32_fp8(nw, false);
            f32x2 n1 = __builtin_amdgcn_cvt_pk_f32_fp8(nw, true);
            float d;
            d = a0[0] - p0[0]; sap = fmaf(d, d, sap);
            d = a0[1] - p0[1]; sap = fmaf(d, d, sap);
            d = a1[0] - p1[0]; sap = fmaf(d, d, sap);
            d = a1[1] - p1[1]; sap = fmaf(d, d, sap);
            d = a0[0] - n0[0]; san = fmaf(d, d, san);
            d = a0[1] - n0[1]; san = fmaf(d, d, san);
            d = a1[0] - n1[0]; san = fmaf(d, d, san);
            d = a1[1] - n1[1]; san = fmaf(d, d, san);
        }
    };

    for (int base = blockIdx.x * 64; base < T; base += gridDim.x * 64) {
        int tA = base + wid * 16 + sub;
        int tB = tA + 8;
        int cA = tA > Tm1 ? Tm1 : tA;
        int cB = tB > Tm1 ? Tm1 : tB;

        // index loads for both triplets first (broadcast within 8-lane group)
        int aA = triplets[3 * cA + 0];
        int pA = triplets[3 * cA + 1];
        int nA = triplets[3 * cA + 2];
        int aB = triplets[3 * cB + 0];
        int pB = triplets[3 * cB + 1];
        int nB = triplets[3 * cB + 2];

        int labA = labels[aA];
        int labB = labels[aB];

        // row loads
        uint4 AA = ldrow(aA);
        uint4 PA = ldrow(pA);
        uint4 NA = ldrow(nA);
        uint4 AB = ldrow(aB);
        uint4 PB = ldrow(pB);
        uint4 NB = ldrow(nB);

        // beta chain resolves while rows are in flight
        float bA = beta[labA];
        float bB = beta[labB];

        float sapA = 0.f, sanA = 0.f, sapB = 0.f, sanB = 0.f;
        accum(AA, PA, NA, sapA, sanA);
        accum(AB, PB, NB, sapB, sanB);

        #pragma unroll
        for (int off = 4; off >= 1; off >>= 1) {
            sapA += __shfl_xor(sapA, off);
            sanA += __shfl_xor(sanA, off);
            sapB += __shfl_xor(sapB, off);
            sanB += __shfl_xor(sanB, off);
        }

        float mA = (tA < T) ? 1.f : 0.f;
        float mB = (tB < T) ? 1.f : 0.f;

        float dapA = sqrtf(sapA + EPS), danA = sqrtf(sanA + EPS);
        float posA = fmaxf(dapA - bA + MARGIN, 0.f);
        float negA = fmaxf(bA - danA + MARGIN, 0.f);
        loss += mA * (posA + negA);
        cnt  += mA * ((posA > 0.f ? 1.f : 0.f) + (negA > 0.f ? 1.f : 0.f));

        float dapB = sqrtf(sapB + EPS), danB = sqrtf(sanB + EPS);
        float posB = fmaxf(dapB - bB + MARGIN, 0.f);
        float negB = fmaxf(bB - danB + MARGIN, 0.f);
        loss += mB * (posB + negB);
        cnt  += mB * ((posB > 0.f ? 1.f : 0.f) + (negB > 0.f ? 1.f : 0.f));
    }

    #pragma unroll
    for (int off = 32; off >= 1; off >>= 1) {
        loss += __shfl_down(loss, off);
        cnt  += __shfl_down(cnt, off);
    }
    __shared__ float sl[4], sc[4];
    if (lane == 0) { sl[wid] = loss; sc[wid] = cnt; }
    __syncthreads();
    if (threadIdx.x == 0) {
        float L = sl[0] + sl[1] + sl[2] + sl[3];
        float C = sc[0] + sc[1] + sc[2] + sc[3];
        atomicAdd(&acc[0], L);
        atomicAdd(&acc[1], C);
        __threadfence();
        unsigned ticket = atomicAdd((unsigned*)acc + 2, 1u);
        if (ticket == gridDim.x - 1) {
            __threadfence();
            float Lt = acc[0] * 0.125f;   // undo 8x duplication
            float Ct = acc[1] * 0.125f;
            out[0] = (Ct > 0.f) ? (Lt / fmaxf(Ct, 1.f)) : Lt;
        }
    }
}

// ---- fp32 fallback (round-3 kernels, known-good, 3 dispatches) ------------

__global__ __launch_bounds__(256) void triplet_loss_f32_kernel(
    const float* __restrict__ batch,
    const int* __restrict__ labels,
    const int* __restrict__ triplets,
    const float* __restrict__ beta,
    float* __restrict__ partial,
    int T)
{
    const int lane = threadIdx.x & 63;
    const int wid  = threadIdx.x >> 6;
    const int sub  = lane >> 3;
    const int fi   = lane & 7;

    float loss = 0.f, cnt = 0.f;

    for (int base = blockIdx.x * 32; base < T; base += gridDim.x * 32) {
        int t = base + wid * 8 + sub;
        if (t < T) {
            int ai = triplets[3 * t + 0];
            int pi = triplets[3 * t + 1];
            int ni = triplets[3 * t + 2];
            float b = beta[labels[ai]];
            const float4* __restrict__ arow = (const float4*)(batch + ((size_t)ai << 7));
            const float4* __restrict__ prow = (const float4*)(batch + ((size_t)pi << 7));
            const float4* __restrict__ nrow = (const float4*)(batch + ((size_t)ni << 7));
            float sap = 0.f, san = 0.f;
            #pragma unroll
            for (int k = 0; k < 4; ++k) {
                float4 av = arow[fi + 8 * k];
                float4 pv = prow[fi + 8 * k];
                float4 nv = nrow[fi + 8 * k];
                float d;
                d = av.x - pv.x; sap += d * d;
                d = av.y - pv.y; sap += d * d;
                d = av.z - pv.z; sap += d * d;
                d = av.w - pv.w; sap += d * d;
                d = av.x - nv.x; san += d * d;
                d = av.y - nv.y; san += d * d;
                d = av.z - nv.z; san += d * d;
                d = av.w - nv.w; san += d * d;
            }
            #pragma unroll
            for (int off = 4; off >= 1; off >>= 1) {
                sap += __shfl_xor(sap, off);
                san += __shfl_xor(san, off);
            }
            float d_ap = sqrtf(sap + EPS);
            float d_an = sqrtf(san + EPS);
            float pos = fmaxf(d_ap - b + MARGIN, 0.f);
            float neg = fmaxf(b - d_an + MARGIN, 0.f);
            loss += pos + neg;
            cnt  += (pos > 0.f ? 1.f : 0.f) + (neg > 0.f ? 1.f : 0.f);
        }
    }

    #pragma unroll
    for (int off = 32; off >= 1; off >>= 1) {
        loss += __shfl_down(loss, off);
        cnt  += __shfl_down(cnt, off);
    }
    __shared__ float sl[4], sc[4];
    if (lane == 0) { sl[wid] = loss; sc[wid] = cnt; }
    __syncthreads();
    if (threadIdx.x == 0) {
        partial[blockIdx.x * 2 + 0] = sl[0] + sl[1] + sl[2] + sl[3];
        partial[blockIdx.x * 2 + 1] = sc[0] + sc[1] + sc[2] + sc[3];
    }
}

__global__ __launch_bounds__(1024) void triplet_finalize_kernel(
    const float* __restrict__ partial, float* __restrict__ out, int nblocks,
    float scale)
{
    float L = 0.f, C = 0.f;
    for (int i = threadIdx.x; i < nblocks; i += blockDim.x) {
        L += partial[2 * i + 0];
        C += partial[2 * i + 1];
    }
    #pragma unroll
    for (int off = 32; off >= 1; off >>= 1) {
        L += __shfl_down(L, off);
        C += __shfl_down(C, off);
    }
    __shared__ float sl[16], sc[16];
    int wid  = threadIdx.x >> 6;
    int lane = threadIdx.x & 63;
    int nw   = blockDim.x >> 6;
    if (lane == 0) { sl[wid] = L; sc[wid] = C; }
    __syncthreads();
    if (threadIdx.x == 0) {
        float Lt = 0.f, Ct = 0.f;
        for (int i = 0; i < nw; ++i) { Lt += sl[i]; Ct += sc[i]; }
        Lt *= scale;
        Ct *= scale;
        out[0] = (Ct > 0.f) ? (Lt / fmaxf(Ct, 1.f)) : Lt;
    }
}

extern "C" void kernel_launch(void* const* d_in, const int* in_sizes, int n_in,
                              void* d_out, int out_size, void* d_ws, size_t ws_size,
                              hipStream_t stream) {
    const float* batch    = (const float*)d_in[0];
    const int*   labels   = (const int*)d_in[1];
    const int*   triplets = (const int*)d_in[2];
    const float* beta     = (const float*)d_in[3];
    float* out = (float*)d_out;

    int nbatch = in_sizes[0];          // 4096*128
    int T = in_sizes[2] / 3;

    size_t f8_bytes = ((size_t)nbatch + 255) & ~(size_t)255;
    size_t need = f8_bytes + 256;

    if (ws_size >= need) {
        unsigned char* batch8 = (unsigned char*)d_ws;
        float* acc            = (float*)((char*)d_ws + f8_bytes);

        int n8 = nbatch / 8;
        convert_kernel<<<(n8 + 255) / 256, 256, 0, stream>>>(batch, batch8, acc, n8);

        int grid = GRID_BLOCKS;
        int groups = (T + 63) / 64;
        if (grid > groups) grid = groups;
        triplet_main_kernel<<<grid, 256, 0, stream>>>(
            batch8, labels, triplets, beta, acc, out, T);
    } else {
        float* partial = (float*)d_ws;
        int grid = GRID_BLOCKS;
        int groups = (T + 31) / 32;
        if (grid > groups) grid = groups;
        triplet_loss_f32_kernel<<<grid, 256, 0, stream>>>(batch, labels, triplets, beta, partial, T);
        triplet_finalize_kernel<<<1, 1024, 0, stream>>>(partial, out, grid, 0.125f);
    }
}

// Round 10
// 44.727 us; speedup vs baseline: 2.1033x; 2.1033x over previous
//
#include <hip/hip_runtime.h>
#include <hip/hip_fp16.h>

#define MARGIN 0.2f
#define EPS 1e-8f

typedef short bf16x8 __attribute__((ext_vector_type(8)));
typedef float f32x4 __attribute__((ext_vector_type(4)));

static __device__ __forceinline__ unsigned short f32_to_bf16(float x) {
    unsigned v = __float_as_uint(x);
    unsigned r = (v + 0x7FFFu + ((v >> 16) & 1u)) >> 16;   // RNE
    return (unsigned short)r;
}

// ---- k1: convert X -> bf16 and compute fp32 row norms ---------------------
// 16 threads per row, 8 floats each; 4-step butterfly within the 16-group.
__global__ __launch_bounds__(256) void prep_norms_kernel(
    const float* __restrict__ batch,
    unsigned short* __restrict__ xb,    // [rows][128] bf16
    float* __restrict__ norms,          // [rows]
    int rows)
{
    int gid = blockIdx.x * blockDim.x + threadIdx.x;
    int r = gid >> 4, c = (gid & 15) * 8;
    if (r >= rows) return;
    const float4* src = (const float4*)(batch + (size_t)r * 128 + c);
    float4 f0 = src[0], f1 = src[1];
    float s = f0.x*f0.x + f0.y*f0.y + f0.z*f0.z + f0.w*f0.w
            + f1.x*f1.x + f1.y*f1.y + f1.z*f1.z + f1.w*f1.w;
    ushort4 u0, u1;
    u0.x = f32_to_bf16(f0.x); u0.y = f32_to_bf16(f0.y);
    u0.z = f32_to_bf16(f0.z); u0.w = f32_to_bf16(f0.w);
    u1.x = f32_to_bf16(f1.x); u1.y = f32_to_bf16(f1.y);
    u1.z = f32_to_bf16(f1.z); u1.w = f32_to_bf16(f1.w);
    *(ushort4*)(xb + (size_t)r * 128 + c)     = u0;
    *(ushort4*)(xb + (size_t)r * 128 + c + 4) = u1;
    #pragma unroll
    for (int off = 8; off >= 1; off >>= 1) s += __shfl_xor(s, off);
    if ((gid & 15) == 0) norms[r] = s;
}

// ---- k2: G = X * X^T via MFMA 16x16x32 bf16, fp16 output ------------------
// 128x128 tile per block, 4 waves each 64x64, K=128 staged once in LDS.
// Fragment layouts (AMD matrix calc / learn_hip m89):
//   A,B: lane l holds elem[row = l&15][k = 8*(l>>4)+j]  (both operands read
//        X[row][k] -> identical addressing; B-transpose comes for free)
//   C/D: col = lane&15, row = (lane>>4)*4 + reg
__global__ __launch_bounds__(256) void gram_kernel(
    const unsigned short* __restrict__ xb,
    __half* __restrict__ G,
    int N)                               // rows (4096), multiple of 128
{
    __shared__ unsigned short Atile[128][136];   // 272B row stride: 16B aligned
    __shared__ unsigned short Btile[128][136];

    int nt = N >> 7;
    int bi = blockIdx.x / nt, bj = blockIdx.x % nt;
    int tid = threadIdx.x;

    #pragma unroll
    for (int pass = 0; pass < 8; ++pass) {
        int r = pass * 16 + (tid >> 4);
        int c = (tid & 15) * 8;
        uint4 av = *(const uint4*)(xb + (size_t)(bi * 128 + r) * 128 + c);
        uint4 bv = *(const uint4*)(xb + (size_t)(bj * 128 + r) * 128 + c);
        *(uint4*)(&Atile[r][c]) = av;
        *(uint4*)(&Btile[r][c]) = bv;
    }
    __syncthreads();

    int w    = tid >> 6;
    int lane = tid & 63;
    int wr = (w >> 1) * 64, wc = (w & 1) * 64;
    int fr = lane & 15, fg = lane >> 4;

    f32x4 acc[4][4] = {};
    #pragma unroll
    for (int ks = 0; ks < 4; ++ks) {
        bf16x8 af[4], bfv[4];
        #pragma unroll
        for (int fm = 0; fm < 4; ++fm)
            af[fm] = *(const bf16x8*)(&Atile[wr + fm * 16 + fr][ks * 32 + fg * 8]);
        #pragma unroll
        for (int fn = 0; fn < 4; ++fn)
            bfv[fn] = *(const bf16x8*)(&Btile[wc + fn * 16 + fr][ks * 32 + fg * 8]);
        #pragma unroll
        for (int fm = 0; fm < 4; ++fm)
            #pragma unroll
            for (int fn = 0; fn < 4; ++fn)
                acc[fm][fn] = __builtin_amdgcn_mfma_f32_16x16x32_bf16(
                    af[fm], bfv[fn], acc[fm][fn], 0, 0, 0);
    }

    int rowbase = bi * 128 + wr, colbase = bj * 128 + wc;
    #pragma unroll
    for (int fm = 0; fm < 4; ++fm)
        #pragma unroll
        for (int fn = 0; fn < 4; ++fn)
            #pragma unroll
            for (int i = 0; i < 4; ++i) {
                int row = rowbase + fm * 16 + fg * 4 + i;
                int col = colbase + fn * 16 + fr;
                G[(size_t)row * N + col] = __float2half(acc[fm][fn][i]);
            }
}

// ---- k3: one thread per triplet; distances from norms + G -----------------
__global__ __launch_bounds__(256) void triplet_kernel(
    const __half* __restrict__ G,
    const float* __restrict__ norms,
    const int* __restrict__ labels,
    const int* __restrict__ triplets,
    const float* __restrict__ beta,
    float* __restrict__ partial,        // [gridDim.x*2]
    int T, int N)
{
    int t = blockIdx.x * blockDim.x + threadIdx.x;
    float loss = 0.f, cnt = 0.f;
    if (t < T) {
        int a = triplets[3 * t + 0];
        int p = triplets[3 * t + 1];
        int n = triplets[3 * t + 2];
        float b  = beta[labels[a]];
        float na = norms[a], npv = norms[p], nn = norms[n];
        float gap = __half2float(G[(size_t)a * N + p]);
        float gan = __half2float(G[(size_t)a * N + n]);
        float dap = sqrtf(fmaxf(na + npv - 2.f * gap, 0.f) + EPS);
        float dan = sqrtf(fmaxf(na + nn  - 2.f * gan, 0.f) + EPS);
        float pos = fmaxf(dap - b + MARGIN, 0.f);
        float neg = fmaxf(b - dan + MARGIN, 0.f);
        loss = pos + neg;
        cnt  = (pos > 0.f ? 1.f : 0.f) + (neg > 0.f ? 1.f : 0.f);
    }
    #pragma unroll
    for (int off = 32; off >= 1; off >>= 1) {
        loss += __shfl_down(loss, off);
        cnt  += __shfl_down(cnt, off);
    }
    __shared__ float sl[4], sc[4];
    int wid = threadIdx.x >> 6, lane = threadIdx.x & 63;
    if (lane == 0) { sl[wid] = loss; sc[wid] = cnt; }
    __syncthreads();
    if (threadIdx.x == 0) {
        partial[blockIdx.x * 2 + 0] = sl[0] + sl[1] + sl[2] + sl[3];
        partial[blockIdx.x * 2 + 1] = sc[0] + sc[1] + sc[2] + sc[3];
    }
}

// ---- k4: finalize ---------------------------------------------------------
__global__ __launch_bounds__(1024) void triplet_finalize_kernel(
    const float* __restrict__ partial, float* __restrict__ out, int nblocks,
    float scale)
{
    float L = 0.f, C = 0.f;
    for (int i = threadIdx.x; i < nblocks; i += blockDim.x) {
        L += partial[2 * i + 0];
        C += partial[2 * i + 1];
    }
    #pragma unroll
    for (int off = 32; off >= 1; off >>= 1) {
        L += __shfl_down(L, off);
        C += __shfl_down(C, off);
    }
    __shared__ float sl[16], sc[16];
    int wid = threadIdx.x >> 6, lane = threadIdx.x & 63;
    int nw = blockDim.x >> 6;
    if (lane == 0) { sl[wid] = L; sc[wid] = C; }
    __syncthreads();
    if (threadIdx.x == 0) {
        float Lt = 0.f, Ct = 0.f;
        for (int i = 0; i < nw; ++i) { Lt += sl[i]; Ct += sc[i]; }
        Lt *= scale; Ct *= scale;
        out[0] = (Ct > 0.f) ? (Lt / fmaxf(Ct, 1.f)) : Lt;
    }
}

// ---- fp32 fallback (round-3 kernel, known-good) ---------------------------
__global__ __launch_bounds__(256) void triplet_loss_f32_kernel(
    const float* __restrict__ batch,
    const int* __restrict__ labels,
    const int* __restrict__ triplets,
    const float* __restrict__ beta,
    float* __restrict__ partial,
    int T)
{
    const int lane = threadIdx.x & 63;
    const int wid  = threadIdx.x >> 6;
    const int sub  = lane >> 3;
    const int fi   = lane & 7;
    float loss = 0.f, cnt = 0.f;
    for (int base = blockIdx.x * 32; base < T; base += gridDim.x * 32) {
        int t = base + wid * 8 + sub;
        if (t < T) {
            int ai = triplets[3 * t + 0];
            int pi = triplets[3 * t + 1];
            int ni = triplets[3 * t + 2];
            float b = beta[labels[ai]];
            const float4* __restrict__ arow = (const float4*)(batch + ((size_t)ai << 7));
            const float4* __restrict__ prow = (const float4*)(batch + ((size_t)pi << 7));
            const float4* __restrict__ nrow = (const float4*)(batch + ((size_t)ni << 7));
            float sap = 0.f, san = 0.f;
            #pragma unroll
            for (int k = 0; k < 4; ++k) {
                float4 av = arow[fi + 8 * k];
                float4 pv = prow[fi + 8 * k];
                float4 nv = nrow[fi + 8 * k];
                float d;
                d = av.x - pv.x; sap += d * d;
                d = av.y - pv.y; sap += d * d;
                d = av.z - pv.z; sap += d * d;
                d = av.w - pv.w; sap += d * d;
                d = av.x - nv.x; san += d * d;
                d = av.y - nv.y; san += d * d;
                d = av.z - nv.z; san += d * d;
                d = av.w - nv.w; san += d * d;
            }
            #pragma unroll
            for (int off = 4; off >= 1; off >>= 1) {
                sap += __shfl_xor(sap, off);
                san += __shfl_xor(san, off);
            }
            float d_ap = sqrtf(sap + EPS);
            float d_an = sqrtf(san + EPS);
            float pos = fmaxf(d_ap - b + MARGIN, 0.f);
            float neg = fmaxf(b - d_an + MARGIN, 0.f);
            loss += pos + neg;
            cnt  += (pos > 0.f ? 1.f : 0.f) + (neg > 0.f ? 1.f : 0.f);
        }
    }
    #pragma unroll
    for (int off = 32; off >= 1; off >>= 1) {
        loss += __shfl_down(loss, off);
        cnt  += __shfl_down(cnt, off);
    }
    __shared__ float sl[4], sc[4];
    if (lane == 0) { sl[wid] = loss; sc[wid] = cnt; }
    __syncthreads();
    if (threadIdx.x == 0) {
        partial[blockIdx.x * 2 + 0] = sl[0] + sl[1] + sl[2] + sl[3];
        partial[blockIdx.x * 2 + 1] = sc[0] + sc[1] + sc[2] + sc[3];
    }
}

extern "C" void kernel_launch(void* const* d_in, const int* in_sizes, int n_in,
                              void* d_out, int out_size, void* d_ws, size_t ws_size,
                              hipStream_t stream) {
    const float* batch    = (const float*)d_in[0];
    const int*   labels   = (const int*)d_in[1];
    const int*   triplets = (const int*)d_in[2];
    const float* beta     = (const float*)d_in[3];
    float* out = (float*)d_out;

    int nbatch = in_sizes[0];           // rows * 128
    int rows   = nbatch / 128;
    int T      = in_sizes[2] / 3;

    size_t xb_bytes    = ((size_t)nbatch * 2 + 255) & ~(size_t)255;
    size_t norms_bytes = ((size_t)rows * 4 + 255) & ~(size_t)255;
    size_t G_bytes     = ((size_t)rows * rows * 2 + 255) & ~(size_t)255;
    int tblocks = (T + 255) / 256;
    size_t part_bytes  = (size_t)tblocks * 2 * sizeof(float);
    size_t need = xb_bytes + norms_bytes + G_bytes + part_bytes;

    bool ok = (rows % 128 == 0) && (nbatch % 128 == 0) && (ws_size >= need);

    if (ok) {
        unsigned short* xb = (unsigned short*)d_ws;
        float* norms       = (float*)((char*)d_ws + xb_bytes);
        __half* G          = (__half*)((char*)d_ws + xb_bytes + norms_bytes);
        float* partial     = (float*)((char*)d_ws + xb_bytes + norms_bytes + G_bytes);

        int k1_threads = rows * 16;
        prep_norms_kernel<<<(k1_threads + 255) / 256, 256, 0, stream>>>(
            batch, xb, norms, rows);

        int nt = rows / 128;
        gram_kernel<<<nt * nt, 256, 0, stream>>>(xb, G, rows);

        triplet_kernel<<<tblocks, 256, 0, stream>>>(
            G, norms, labels, triplets, beta, partial, T, rows);

        triplet_finalize_kernel<<<1, 1024, 0, stream>>>(partial, out, tblocks, 1.0f);
    } else {
        float* partial = (float*)d_ws;
        int grid = 2048;
        int groups = (T + 31) / 32;
        if (grid > groups) grid = groups;
        triplet_loss_f32_kernel<<<grid, 256, 0, stream>>>(batch, labels, triplets, beta, partial, T);
        triplet_finalize_kernel<<<1, 1024, 0, stream>>>(partial, out, grid, 0.125f);
    }
}

// Round 11
// 32.831 us; speedup vs baseline: 2.8653x; 1.3623x over previous
//
#include <hip/hip_runtime.h>

#define MARGIN 0.2f
#define EPS 1e-8f
#define GRID_BLOCKS 2048

typedef float f32x2 __attribute__((ext_vector_type(2)));

// async global->LDS, 16B per lane; dest = wave-uniform base + lane*16,
// source = per-lane address (gather-capable per learn_hip m104/m108)
__device__ __forceinline__ void gload_lds16(const unsigned char* g, uint4* l) {
    __builtin_amdgcn_global_load_lds(
        (const __attribute__((address_space(1))) unsigned int*)(g),
        (__attribute__((address_space(3))) unsigned int*)(l), 16, 0, 0);
}

// ---- prep: fp32->fp8(e4m3) convert + per-triplet {aoff,poff,noff,beta} ----

__global__ __launch_bounds__(256) void prep_kernel(
    const float* __restrict__ batch,
    const int* __restrict__ labels,
    const int* __restrict__ triplets,
    const float* __restrict__ beta,
    unsigned char* __restrict__ batch8,
    int4* __restrict__ prep,
    int n8, int T)
{
    int i = blockIdx.x * blockDim.x + threadIdx.x;
    if (i < n8) {
        const float4* src = (const float4*)(batch + (size_t)i * 8);
        float4 f0 = src[0];
        float4 f1 = src[1];
        int lo = __builtin_amdgcn_cvt_pk_fp8_f32(f0.x, f0.y, 0, false);
        lo     = __builtin_amdgcn_cvt_pk_fp8_f32(f0.z, f0.w, lo, true);
        int hi = __builtin_amdgcn_cvt_pk_fp8_f32(f1.x, f1.y, 0, false);
        hi     = __builtin_amdgcn_cvt_pk_fp8_f32(f1.z, f1.w, hi, true);
        uint2 w;
        w.x = (unsigned)lo;
        w.y = (unsigned)hi;
        *(uint2*)(batch8 + (size_t)i * 8) = w;
    }
    if (i < T) {
        int a = triplets[3 * i + 0];
        int p = triplets[3 * i + 1];
        int n = triplets[3 * i + 2];
        float b = beta[labels[a]];
        int4 s;
        s.x = a << 7;               // byte offset of row (128 B/row in fp8)
        s.y = p << 7;
        s.z = n << 7;
        s.w = __float_as_int(b);
        prep[i] = s;
    }
}

// ---- main: fp8 rows gathered via global_load_lds DMA ----------------------
// 8 lanes/triplet, 8 triplets per wave per iteration. One global_load_lds
// instruction fetches the A-rows (or P, or N) of all 8 triplets: lane L
// (group g=L>>3, chunk c=L&7) sources batch8[rowoff(g)] + c*16 and the DMA
// lands it at stage[wave][m] + L*16 -> readback at lane*16 is LINEAR (no
// bank conflicts, no swizzle). Rows never occupy VGPRs while in flight, so
// in-flight bytes/CU ~ waves * 3KB >> the ~3KB VGPR-return cap that pinned
// rounds 4-8 at ~31us (Little's law).
__global__ __launch_bounds__(256) void triplet_main_kernel(
    const unsigned char* __restrict__ batch8,
    const int4* __restrict__ prep,
    float* __restrict__ partial,   // [gridDim.x * 2], 8x-scaled
    int T)
{
    __shared__ uint4 stage[4][3][64];   // [wave][m=A/P/N][lane]

    const int lane = threadIdx.x & 63;
    const int wid  = threadIdx.x >> 6;   // wave 0..3
    const int sub  = lane >> 3;          // triplet slot 0..7
    const int co   = (lane & 7) << 4;    // chunk byte offset 0..112

    const int stride = gridDim.x * 32;   // 32 triplets per block per iter
    const int myoff  = wid * 8 + sub;
    const int Tm1 = T - 1;

    float loss = 0.f, cnt = 0.f;

    auto cl = [&](int x) { return x > Tm1 ? Tm1 : x; };
    auto accum = [&](const uint4& A, const uint4& P, const uint4& N,
                     float& sap, float& san) {
        #pragma unroll
        for (int w = 0; w < 4; ++w) {
            unsigned aw = (&A.x)[w];
            unsigned pw = (&P.x)[w];
            unsigned nw = (&N.x)[w];
            f32x2 a0 = __builtin_amdgcn_cvt_pk_f32_fp8(aw, false);
            f32x2 a1 = __builtin_amdgcn_cvt_pk_f32_fp8(aw, true);
            f32x2 p0 = __builtin_amdgcn_cvt_pk_f32_fp8(pw, false);
            f32x2 p1 = __builtin_amdgcn_cvt_pk_f32_fp8(pw, true);
            f32x2 n0 = __builtin_amdgcn_cvt_pk_f32_fp8(nw, false);
            f32x2 n1 = __builtin_amdgcn_cvt_pk_f32_fp8(nw, true);
            float d;
            d = a0[0] - p0[0]; sap = fmaf(d, d, sap);
            d = a0[1] - p0[1]; sap = fmaf(d, d, sap);
            d = a1[0] - p1[0]; sap = fmaf(d, d, sap);
            d = a1[1] - p1[1]; sap = fmaf(d, d, sap);
            d = a0[0] - n0[0]; san = fmaf(d, d, san);
            d = a0[1] - n0[1]; san = fmaf(d, d, san);
            d = a1[0] - n1[0]; san = fmaf(d, d, san);
            d = a1[1] - n1[1]; san = fmaf(d, d, san);
        }
    };

    int base = blockIdx.x * 32;          // grid <= ceil(T/32) so base < T
    int t = base + myoff;

    // prologue: prep for iter0 -> issue iter0 staging; prefetch prep iter1
    int4 sc = prep[cl(t)];
    gload_lds16(batch8 + (unsigned)sc.x + co, &stage[wid][0][0]);
    gload_lds16(batch8 + (unsigned)sc.y + co, &stage[wid][1][0]);
    gload_lds16(batch8 + (unsigned)sc.z + co, &stage[wid][2][0]);
    int4 sn = prep[cl(t + stride)];

    for (; base < T; base += stride, t += stride) {
        // wait: current staging (and the prep prefetch) have landed
        asm volatile("s_waitcnt vmcnt(0)" ::: "memory");
        __builtin_amdgcn_sched_barrier(0);

        uint4 A = stage[wid][0][lane];
        uint4 P = stage[wid][1][lane];
        uint4 N = stage[wid][2][lane];
        asm volatile("s_waitcnt lgkmcnt(0)" ::: "memory");
        __builtin_amdgcn_sched_barrier(0);

        // issue next-iteration staging; its latency hides under the decode
        if (base + stride < T) {
            gload_lds16(batch8 + (unsigned)sn.x + co, &stage[wid][0][0]);
            gload_lds16(batch8 + (unsigned)sn.y + co, &stage[wid][1][0]);
            gload_lds16(batch8 + (unsigned)sn.z + co, &stage[wid][2][0]);
        }
        int4 sn2 = prep[cl(t + 2 * stride)];

        float sap = 0.f, san = 0.f;
        accum(A, P, N, sap, san);

        #pragma unroll
        for (int off = 4; off >= 1; off >>= 1) {
            sap += __shfl_xor(sap, off);
            san += __shfl_xor(san, off);
        }

        float b = __int_as_float(sc.w);
        float m = (t < T) ? 1.f : 0.f;
        float dap = sqrtf(sap + EPS), dan = sqrtf(san + EPS);
        float pos = fmaxf(dap - b + MARGIN, 0.f);
        float neg = fmaxf(b - dan + MARGIN, 0.f);
        loss += m * (pos + neg);
        cnt  += m * ((pos > 0.f ? 1.f : 0.f) + (neg > 0.f ? 1.f : 0.f));

        sc = sn; sn = sn2;
    }

    // drain any outstanding prep prefetch before LDS reuse / exit
    asm volatile("s_waitcnt vmcnt(0)" ::: "memory");

    #pragma unroll
    for (int off = 32; off >= 1; off >>= 1) {
        loss += __shfl_down(loss, off);
        cnt  += __shfl_down(cnt, off);
    }
    __shared__ float sl[4], sc_[4];
    if (lane == 0) { sl[wid] = loss; sc_[wid] = cnt; }
    __syncthreads();
    if (threadIdx.x == 0) {
        partial[blockIdx.x * 2 + 0] = sl[0] + sl[1] + sl[2] + sl[3];
        partial[blockIdx.x * 2 + 1] = sc_[0] + sc_[1] + sc_[2] + sc_[3];
    }
}

// ---- fp32 fallback (round-3 kernel, known-good) ---------------------------

__global__ __launch_bounds__(256) void triplet_loss_f32_kernel(
    const float* __restrict__ batch,
    const int* __restrict__ labels,
    const int* __restrict__ triplets,
    const float* __restrict__ beta,
    float* __restrict__ partial,
    int T)
{
    const int lane = threadIdx.x & 63;
    const int wid  = threadIdx.x >> 6;
    const int sub  = lane >> 3;
    const int fi   = lane & 7;

    float loss = 0.f, cnt = 0.f;

    for (int base = blockIdx.x * 32; base < T; base += gridDim.x * 32) {
        int t = base + wid * 8 + sub;
        if (t < T) {
            int ai = triplets[3 * t + 0];
            int pi = triplets[3 * t + 1];
            int ni = triplets[3 * t + 2];
            float b = beta[labels[ai]];
            const float4* __restrict__ arow = (const float4*)(batch + ((size_t)ai << 7));
            const float4* __restrict__ prow = (const float4*)(batch + ((size_t)pi << 7));
            const float4* __restrict__ nrow = (const float4*)(batch + ((size_t)ni << 7));
            float sap = 0.f, san = 0.f;
            #pragma unroll
            for (int k = 0; k < 4; ++k) {
                float4 av = arow[fi + 8 * k];
                float4 pv = prow[fi + 8 * k];
                float4 nv = nrow[fi + 8 * k];
                float d;
                d = av.x - pv.x; sap += d * d;
                d = av.y - pv.y; sap += d * d;
                d = av.z - pv.z; sap += d * d;
                d = av.w - pv.w; sap += d * d;
                d = av.x - nv.x; san += d * d;
                d = av.y - nv.y; san += d * d;
                d = av.z - nv.z; san += d * d;
                d = av.w - nv.w; san += d * d;
            }
            #pragma unroll
            for (int off = 4; off >= 1; off >>= 1) {
                sap += __shfl_xor(sap, off);
                san += __shfl_xor(san, off);
            }
            float d_ap = sqrtf(sap + EPS);
            float d_an = sqrtf(san + EPS);
            float pos = fmaxf(d_ap - b + MARGIN, 0.f);
            float neg = fmaxf(b - d_an + MARGIN, 0.f);
            loss += pos + neg;
            cnt  += (pos > 0.f ? 1.f : 0.f) + (neg > 0.f ? 1.f : 0.f);
        }
    }

    #pragma unroll
    for (int off = 32; off >= 1; off >>= 1) {
        loss += __shfl_down(loss, off);
        cnt  += __shfl_down(cnt, off);
    }
    __shared__ float sl[4], sc[4];
    if (lane == 0) { sl[wid] = loss; sc[wid] = cnt; }
    __syncthreads();
    if (threadIdx.x == 0) {
        partial[blockIdx.x * 2 + 0] = sl[0] + sl[1] + sl[2] + sl[3];
        partial[blockIdx.x * 2 + 1] = sc[0] + sc[1] + sc[2] + sc[3];
    }
}

// ---- finalize --------------------------------------------------------------

__global__ __launch_bounds__(1024) void triplet_finalize_kernel(
    const float* __restrict__ partial, float* __restrict__ out, int nblocks,
    float scale)
{
    float L = 0.f, C = 0.f;
    for (int i = threadIdx.x; i < nblocks; i += blockDim.x) {
        L += partial[2 * i + 0];
        C += partial[2 * i + 1];
    }
    #pragma unroll
    for (int off = 32; off >= 1; off >>= 1) {
        L += __shfl_down(L, off);
        C += __shfl_down(C, off);
    }
    __shared__ float sl[16], sc[16];
    int wid  = threadIdx.x >> 6;
    int lane = threadIdx.x & 63;
    int nw   = blockDim.x >> 6;
    if (lane == 0) { sl[wid] = L; sc[wid] = C; }
    __syncthreads();
    if (threadIdx.x == 0) {
        float Lt = 0.f, Ct = 0.f;
        for (int i = 0; i < nw; ++i) { Lt += sl[i]; Ct += sc[i]; }
        Lt *= scale;
        Ct *= scale;
        out[0] = (Ct > 0.f) ? (Lt / fmaxf(Ct, 1.f)) : Lt;
    }
}

extern "C" void kernel_launch(void* const* d_in, const int* in_sizes, int n_in,
                              void* d_out, int out_size, void* d_ws, size_t ws_size,
                              hipStream_t stream) {
    const float* batch    = (const float*)d_in[0];
    const int*   labels   = (const int*)d_in[1];
    const int*   triplets = (const int*)d_in[2];
    const float* beta     = (const float*)d_in[3];
    float* out = (float*)d_out;

    int nbatch = in_sizes[0];          // 4096*128
    int T = in_sizes[2] / 3;

    size_t f8_bytes   = ((size_t)nbatch + 255) & ~(size_t)255;
    size_t prep_bytes = ((size_t)T * sizeof(int4) + 255) & ~(size_t)255;
    size_t need = f8_bytes + prep_bytes + (size_t)GRID_BLOCKS * 2 * sizeof(float);

    if (ws_size >= need) {
        unsigned char* batch8 = (unsigned char*)d_ws;
        int4* prep            = (int4*)((char*)d_ws + f8_bytes);
        float* partial        = (float*)((char*)d_ws + f8_bytes + prep_bytes);

        int n8 = nbatch / 8;
        int prep_items = (T > n8) ? T : n8;
        prep_kernel<<<(prep_items + 255) / 256, 256, 0, stream>>>(
            batch, labels, triplets, beta, batch8, prep, n8, T);

        int grid = GRID_BLOCKS;
        int groups = (T + 31) / 32;
        if (grid > groups) grid = groups;
        triplet_main_kernel<<<grid, 256, 0, stream>>>(batch8, prep, partial, T);
        triplet_finalize_kernel<<<1, 1024, 0, stream>>>(partial, out, grid, 0.125f);
    } else {
        float* partial = (float*)d_ws;
        int grid = GRID_BLOCKS;
        int groups = (T + 31) / 32;
        if (grid > groups) grid = groups;
        triplet_loss_f32_kernel<<<grid, 256, 0, stream>>>(batch, labels, triplets, beta, partial, T);
        triplet_finalize_kernel<<<1, 1024, 0, stream>>>(partial, out, grid, 0.125f);
    }
}

// Round 12
// 31.690 us; speedup vs baseline: 2.9685x; 1.0360x over previous
//
#include <hip/hip_runtime.h>

#define MARGIN 0.2f
#define EPS 1e-8f
#define GRID_BLOCKS 2048

typedef float f32x2 __attribute__((ext_vector_type(2)));

// ---- prep: fp32->fp8(e4m3) convert + per-triplet {aoff,poff,noff,beta} ----

__global__ __launch_bounds__(256) void prep_kernel(
    const float* __restrict__ batch,
    const int* __restrict__ labels,
    const int* __restrict__ triplets,
    const float* __restrict__ beta,
    unsigned char* __restrict__ batch8,
    int4* __restrict__ prep,
    int n8, int T)
{
    int i = blockIdx.x * blockDim.x + threadIdx.x;
    if (i < n8) {
        const float4* src = (const float4*)(batch + (size_t)i * 8);
        float4 f0 = src[0];
        float4 f1 = src[1];
        int lo = __builtin_amdgcn_cvt_pk_fp8_f32(f0.x, f0.y, 0, false);
        lo     = __builtin_amdgcn_cvt_pk_fp8_f32(f0.z, f0.w, lo, true);
        int hi = __builtin_amdgcn_cvt_pk_fp8_f32(f1.x, f1.y, 0, false);
        hi     = __builtin_amdgcn_cvt_pk_fp8_f32(f1.z, f1.w, hi, true);
        uint2 w;
        w.x = (unsigned)lo;
        w.y = (unsigned)hi;
        *(uint2*)(batch8 + (size_t)i * 8) = w;
    }
    if (i < T) {
        int a = triplets[3 * i + 0];
        int p = triplets[3 * i + 1];
        int n = triplets[3 * i + 2];
        float b = beta[labels[a]];
        int4 s;
        s.x = a << 7;               // byte offset of row (128 B/row in fp8)
        s.y = p << 7;
        s.z = n << 7;
        s.w = __float_as_int(b);
        prep[i] = s;
    }
}

// ---- main: fp8 rows, 8 lanes/triplet, unroll x2, PACKED-f32 math ----------
// Row = 128 fp8 = 128B; lane fi loads uint4 at byte fi*16 (one wave
// instruction per row covers 8 triplets' rows). Decode keeps everything in
// f32x2 lanes-of-2: cvt_pk_f32_fp8 emits f32x2, diffs/squares stay packed
// (v_pk_add_f32 / v_pk_fma_f32) -> 14 VALU per 4 elems vs 22 scalar.
// This cuts the decode VALU stream ~40% -- the R11 analysis says fp8's
// binder was decode-VALU + exposed latency, not bytes/requests.
__global__ __launch_bounds__(256) void triplet_main_kernel(
    const unsigned char* __restrict__ batch8,
    const int4* __restrict__ prep,
    float* __restrict__ partial,   // [gridDim.x * 2], 8x-scaled
    int T)
{
    const int lane = threadIdx.x & 63;
    const int wid  = threadIdx.x >> 6;   // wave 0..3
    const int sub  = lane >> 3;          // triplet slot 0..7
    const int fi   = lane & 7;           // 16B chunk 0..7 within row
    const int boff = fi << 4;

    float loss = 0.f, cnt = 0.f;
    const int Tm1 = T - 1;

    auto ldrow = [&](int off) {
        return *(const uint4*)(batch8 + (size_t)(unsigned)off + boff);
    };
    auto accum = [&](const uint4& A, const uint4& P, const uint4& N,
                     f32x2& sap2, f32x2& san2) {
        #pragma unroll
        for (int w = 0; w < 4; ++w) {
            unsigned aw = (&A.x)[w];
            unsigned pw = (&P.x)[w];
            unsigned nw = (&N.x)[w];
            f32x2 a0 = __builtin_amdgcn_cvt_pk_f32_fp8(aw, false);
            f32x2 a1 = __builtin_amdgcn_cvt_pk_f32_fp8(aw, true);
            f32x2 p0 = __builtin_amdgcn_cvt_pk_f32_fp8(pw, false);
            f32x2 p1 = __builtin_amdgcn_cvt_pk_f32_fp8(pw, true);
            f32x2 n0 = __builtin_amdgcn_cvt_pk_f32_fp8(nw, false);
            f32x2 n1 = __builtin_amdgcn_cvt_pk_f32_fp8(nw, true);
            f32x2 d0 = a0 - p0;
            f32x2 d1 = a1 - p1;
            sap2 = d0 * d0 + sap2;     // v_pk_fma_f32
            sap2 = d1 * d1 + sap2;
            f32x2 e0 = a0 - n0;
            f32x2 e1 = a1 - n1;
            san2 = e0 * e0 + san2;
            san2 = e1 * e1 + san2;
        }
    };

    for (int base = blockIdx.x * 64; base < T; base += gridDim.x * 64) {
        int tA = base + wid * 16 + sub;
        int tB = tA + 8;
        int cA = tA > Tm1 ? Tm1 : tA;
        int cB = tB > Tm1 ? Tm1 : tB;
        int4 sA = prep[cA];
        int4 sB = prep[cB];

        uint4 AA = ldrow(sA.x);
        uint4 PA = ldrow(sA.y);
        uint4 NA = ldrow(sA.z);
        uint4 AB = ldrow(sB.x);
        uint4 PB = ldrow(sB.y);
        uint4 NB = ldrow(sB.z);

        f32x2 sapA2 = {0.f, 0.f}, sanA2 = {0.f, 0.f};
        f32x2 sapB2 = {0.f, 0.f}, sanB2 = {0.f, 0.f};
        accum(AA, PA, NA, sapA2, sanA2);
        accum(AB, PB, NB, sapB2, sanB2);

        float sapA = sapA2[0] + sapA2[1];
        float sanA = sanA2[0] + sanA2[1];
        float sapB = sapB2[0] + sapB2[1];
        float sanB = sanB2[0] + sanB2[1];

        // butterfly across the 8-lane group
        #pragma unroll
        for (int off = 4; off >= 1; off >>= 1) {
            sapA += __shfl_xor(sapA, off);
            sanA += __shfl_xor(sanA, off);
            sapB += __shfl_xor(sapB, off);
            sanB += __shfl_xor(sanB, off);
        }

        float bA = __int_as_float(sA.w);
        float bB = __int_as_float(sB.w);
        float mA = (tA < T) ? 1.f : 0.f;
        float mB = (tB < T) ? 1.f : 0.f;

        float dapA = sqrtf(sapA + EPS), danA = sqrtf(sanA + EPS);
        float posA = fmaxf(dapA - bA + MARGIN, 0.f);
        float negA = fmaxf(bA - danA + MARGIN, 0.f);
        loss += mA * (posA + negA);
        cnt  += mA * ((posA > 0.f ? 1.f : 0.f) + (negA > 0.f ? 1.f : 0.f));

        float dapB = sqrtf(sapB + EPS), danB = sqrtf(sanB + EPS);
        float posB = fmaxf(dapB - bB + MARGIN, 0.f);
        float negB = fmaxf(bB - danB + MARGIN, 0.f);
        loss += mB * (posB + negB);
        cnt  += mB * ((posB > 0.f ? 1.f : 0.f) + (negB > 0.f ? 1.f : 0.f));
    }

    #pragma unroll
    for (int off = 32; off >= 1; off >>= 1) {
        loss += __shfl_down(loss, off);
        cnt  += __shfl_down(cnt, off);
    }
    __shared__ float sl[4], sc[4];
    if (lane == 0) { sl[wid] = loss; sc[wid] = cnt; }
    __syncthreads();
    if (threadIdx.x == 0) {
        partial[blockIdx.x * 2 + 0] = sl[0] + sl[1] + sl[2] + sl[3];
        partial[blockIdx.x * 2 + 1] = sc[0] + sc[1] + sc[2] + sc[3];
    }
}

// ---- fp32 fallback (round-3 kernel, known-good) ---------------------------

__global__ __launch_bounds__(256) void triplet_loss_f32_kernel(
    const float* __restrict__ batch,
    const int* __restrict__ labels,
    const int* __restrict__ triplets,
    const float* __restrict__ beta,
    float* __restrict__ partial,
    int T)
{
    const int lane = threadIdx.x & 63;
    const int wid  = threadIdx.x >> 6;
    const int sub  = lane >> 3;
    const int fi   = lane & 7;

    float loss = 0.f, cnt = 0.f;

    for (int base = blockIdx.x * 32; base < T; base += gridDim.x * 32) {
        int t = base + wid * 8 + sub;
        if (t < T) {
            int ai = triplets[3 * t + 0];
            int pi = triplets[3 * t + 1];
            int ni = triplets[3 * t + 2];
            float b = beta[labels[ai]];
            const float4* __restrict__ arow = (const float4*)(batch + ((size_t)ai << 7));
            const float4* __restrict__ prow = (const float4*)(batch + ((size_t)pi << 7));
            const float4* __restrict__ nrow = (const float4*)(batch + ((size_t)ni << 7));
            float sap = 0.f, san = 0.f;
            #pragma unroll
            for (int k = 0; k < 4; ++k) {
                float4 av = arow[fi + 8 * k];
                float4 pv = prow[fi + 8 * k];
                float4 nv = nrow[fi + 8 * k];
                float d;
                d = av.x - pv.x; sap += d * d;
                d = av.y - pv.y; sap += d * d;
                d = av.z - pv.z; sap += d * d;
                d = av.w - pv.w; sap += d * d;
                d = av.x - nv.x; san += d * d;
                d = av.y - nv.y; san += d * d;
                d = av.z - nv.z; san += d * d;
                d = av.w - nv.w; san += d * d;
            }
            #pragma unroll
            for (int off = 4; off >= 1; off >>= 1) {
                sap += __shfl_xor(sap, off);
                san += __shfl_xor(san, off);
            }
            float d_ap = sqrtf(sap + EPS);
            float d_an = sqrtf(san + EPS);
            float pos = fmaxf(d_ap - b + MARGIN, 0.f);
            float neg = fmaxf(b - d_an + MARGIN, 0.f);
            loss += pos + neg;
            cnt  += (pos > 0.f ? 1.f : 0.f) + (neg > 0.f ? 1.f : 0.f);
        }
    }

    #pragma unroll
    for (int off = 32; off >= 1; off >>= 1) {
        loss += __shfl_down(loss, off);
        cnt  += __shfl_down(cnt, off);
    }
    __shared__ float sl[4], sc[4];
    if (lane == 0) { sl[wid] = loss; sc[wid] = cnt; }
    __syncthreads();
    if (threadIdx.x == 0) {
        partial[blockIdx.x * 2 + 0] = sl[0] + sl[1] + sl[2] + sl[3];
        partial[blockIdx.x * 2 + 1] = sc[0] + sc[1] + sc[2] + sc[3];
    }
}

// ---- finalize --------------------------------------------------------------

__global__ __launch_bounds__(1024) void triplet_finalize_kernel(
    const float* __restrict__ partial, float* __restrict__ out, int nblocks,
    float scale)
{
    float L = 0.f, C = 0.f;
    for (int i = threadIdx.x; i < nblocks; i += blockDim.x) {
        L += partial[2 * i + 0];
        C += partial[2 * i + 1];
    }
    #pragma unroll
    for (int off = 32; off >= 1; off >>= 1) {
        L += __shfl_down(L, off);
        C += __shfl_down(C, off);
    }
    __shared__ float sl[16], sc[16];
    int wid  = threadIdx.x >> 6;
    int lane = threadIdx.x & 63;
    int nw   = blockDim.x >> 6;
    if (lane == 0) { sl[wid] = L; sc[wid] = C; }
    __syncthreads();
    if (threadIdx.x == 0) {
        float Lt = 0.f, Ct = 0.f;
        for (int i = 0; i < nw; ++i) { Lt += sl[i]; Ct += sc[i]; }
        Lt *= scale;
        Ct *= scale;
        out[0] = (Ct > 0.f) ? (Lt / fmaxf(Ct, 1.f)) : Lt;
    }
}

extern "C" void kernel_launch(void* const* d_in, const int* in_sizes, int n_in,
                              void* d_out, int out_size, void* d_ws, size_t ws_size,
                              hipStream_t stream) {
    const float* batch    = (const float*)d_in[0];
    const int*   labels   = (const int*)d_in[1];
    const int*   triplets = (const int*)d_in[2];
    const float* beta     = (const float*)d_in[3];
    float* out = (float*)d_out;

    int nbatch = in_sizes[0];          // 4096*128
    int T = in_sizes[2] / 3;

    size_t f8_bytes   = ((size_t)nbatch + 255) & ~(size_t)255;
    size_t prep_bytes = ((size_t)T * sizeof(int4) + 255) & ~(size_t)255;
    size_t need = f8_bytes + prep_bytes + (size_t)GRID_BLOCKS * 2 * sizeof(float);

    if (ws_size >= need) {
        unsigned char* batch8 = (unsigned char*)d_ws;
        int4* prep            = (int4*)((char*)d_ws + f8_bytes);
        float* partial        = (float*)((char*)d_ws + f8_bytes + prep_bytes);

        int n8 = nbatch / 8;
        int prep_items = (T > n8) ? T : n8;
        prep_kernel<<<(prep_items + 255) / 256, 256, 0, stream>>>(
            batch, labels, triplets, beta, batch8, prep, n8, T);

        int grid = GRID_BLOCKS;
        int groups = (T + 63) / 64;
        if (grid > groups) grid = groups;
        triplet_main_kernel<<<grid, 256, 0, stream>>>(batch8, prep, partial, T);
        triplet_finalize_kernel<<<1, 1024, 0, stream>>>(partial, out, grid, 0.125f);
    } else {
        float* partial = (float*)d_ws;
        int grid = GRID_BLOCKS;
        int groups = (T + 31) / 32;
        if (grid > groups) grid = groups;
        triplet_loss_f32_kernel<<<grid, 256, 0, stream>>>(batch, labels, triplets, beta, partial, T);
        triplet_finalize_kernel<<<1, 1024, 0, stream>>>(partial, out, grid, 0.125f);
    }
}